// Round 10
// baseline (133.559 us; speedup 1.0000x reference)
//
#include <hip/hip_runtime.h>
#include <hip/hip_bf16.h>

#define N_ROWS 8192
#define DIM 256
#define NANCH 64
#define NVIEW 128
#define NPART 16    // column partitions (4 anchors = 512 cols each)

typedef __attribute__((ext_vector_type(8))) short bf16x8;
typedef __attribute__((ext_vector_type(16))) float f32x16;
typedef __attribute__((ext_vector_type(4))) float float4v;
typedef __attribute__((ext_vector_type(4))) unsigned short ushort4v;

__device__ __forceinline__ unsigned short f2bf(float x) {
  union { float f; unsigned int u; } c; c.f = x;
  unsigned int u = c.u;
  unsigned int r = (u + 0x7fffu + ((u >> 16) & 1u)) >> 16;
  return (unsigned short)r;
}

__device__ __forceinline__ float bf2f(unsigned short b) {
  union { unsigned int u; float f; } c; c.u = ((unsigned int)b) << 16;
  return c.f;
}

__device__ __forceinline__ void gload_lds16(const void* g, void* l) {
  __builtin_amdgcn_global_load_lds(
      (const __attribute__((address_space(1))) unsigned int*)g,
      (__attribute__((address_space(3))) unsigned int*)l, 16, 0, 0);
}

// fp32 -> bf16 with 1/sqrt(T) prescale, fused with per-row squared-norm
// (= the Gram diagonal = the row max of the logits). One wave per row.
__global__ void cast_diag_kernel(const float4v* __restrict__ in,
                                 ushort4v* __restrict__ out,
                                 float* __restrict__ diag) {
  const int w = threadIdx.x >> 6;
  const int l = threadIdx.x & 63;
  const int row = blockIdx.x * 4 + w;
  const float s = 3.16227766016838f; // 1/sqrt(0.1)
  float4v v = in[row * 64 + l];
  ushort4v o;
  o.x = f2bf(v.x * s);
  o.y = f2bf(v.y * s);
  o.z = f2bf(v.z * s);
  o.w = f2bf(v.w * s);
  out[row * 64 + l] = o;
  float c0 = bf2f(o.x), c1 = bf2f(o.y), c2 = bf2f(o.z), c3 = bf2f(o.w);
  float ss = c0 * c0 + c1 * c1 + c2 * c2 + c3 * c3;
#pragma unroll
  for (int st = 1; st < 64; st <<= 1) ss += __shfl_xor(ss, st);
  if (l == 0) diag[row] = ss;
}

// -------- Kernel 2: fused pass over (256 rows x 512 cols) per block.
// grid = 32 row-blocks x 16 parts = 512 blocks; 256 threads = 4 waves, each
// wave owns 64 rows x 32 cols. LDS = 3-slot ring of 16 KB tiles (32 cols x
// K=256, k-major conflict-free) + meta ~= 53.5 KB -> TWO co-resident blocks
// per CU even under a 128-KB pool (round-9's 66.5-KB block got only 1/CU ->
// the whole regression). Two independent blocks overlap each other's
// barrier/vmcnt stalls (m114). Counted vmcnt(8) (4 loads/thread/tile,
// prefetch depth 2), never 0 mid-loop. Row max is KNOWN (= diag).
// NEGATIVE anchors -> ns += exp(v - diag)  [underflow-skipped]
// POSITIVE anchors -> sd += (v - diag)     [always; diagonal masked]
//                     ep += exp(v - diag)  [underflow-skipped, diag masked]
__global__ __launch_bounds__(256, 2) void pcl_negsum(
    const unsigned short* __restrict__ Xb, const int* __restrict__ labels,
    const float* __restrict__ diag, float* __restrict__ ns_partial,
    float* __restrict__ sd_partial, float* __restrict__ ep_partial) {
  const int bx = blockIdx.x;
  const int rb = bx & 31;             // row block: rows rb*256 .. +255
  const int part = bx >> 5;           // 0..15 -> col anchors part*4 .. +3
  const int abase = part * 4;
  const int tid = threadIdx.x;        // 0..255
  const int wid = tid >> 6;           // 0..3 -> row group (64 rows)
  const int lane = tid & 63;
  const int l31 = lane & 31;
  const int khalf = lane >> 5;
  const int R0 = rb * 256;

  __shared__ __align__(16) unsigned short ring[3 * 32 * DIM];  // 3 x 16 KB
  __shared__ float sdiag[256];
  __shared__ float nsacc[256];
  __shared__ float sdacc[256];
  __shared__ float epacc[256];
  __shared__ int slab[NANCH];

  if (tid < NANCH) slab[tid] = labels[tid];
  if (tid < 256) {
    sdiag[tid] = diag[R0 + tid];
    nsacc[tid] = 0.f;
    sdacc[tid] = 0.f;
    epacc[tid] = 0.f;
  }
  __syncthreads();
  // wave's rows all lie in anchor rb*2 + (wid>>1)
  const int myAnch = rb * 2 + (wid >> 1);
  const int myLab = slab[myAnch];

  // A fragments: lane holds row R0 + wid*64 + ri*32 + l31, k = ks*16+khalf*8.
  bf16x8 afrag[2][16];
#pragma unroll
  for (int ri = 0; ri < 2; ++ri) {
#pragma unroll
    for (int ks = 0; ks < 16; ++ks) {
      const unsigned short* p =
          Xb + (size_t)(R0 + wid * 64 + ri * 32 + l31) * DIM + ks * 16 + khalf * 8;
      afrag[ri][ks] = *(const bf16x8*)p;
    }
  }
#pragma unroll
  for (int ri = 0; ri < 2; ++ri)
#pragma unroll
    for (int ks = 0; ks < 16; ++ks) asm volatile("" : "+v"(afrag[ri][ks]));

  // Wave-uniform skip threshold: min diag over this wave's 64 rows - 40.
  float thr;
  {
    float d = sdiag[wid * 64 + lane];
#pragma unroll
    for (int st = 1; st < 64; st <<= 1) d = fminf(d, __shfl_xor(d, st));
    thr = d - 40.f;
  }

  char* const L0 = (char*)&ring[0];

  // Tile S (0..15): anchor abase+(S>>2), col quarter (S&3)*32. k-major LDS
  // [k-octet 0..31][col 0..31][16B]. Thread covers chunks g = i*256+tid:
  // k-octet = i*8 + wid*2 + khalf, col = l31. 4 gload_lds16 per thread.
#define STAGE(H)                                                                \
  do {                                                                          \
    const int _cb = (abase + ((H) >> 2)) * NVIEW + ((H) & 3) * 32;              \
    const unsigned short* _s =                                                  \
        Xb + (size_t)(_cb + l31) * DIM + (wid * 2 + khalf) * 8;                 \
    char* _d = L0 + ((H) % 3) * 16384 + wid * 1024;                             \
    gload_lds16(_s, _d);                                                        \
    gload_lds16(_s + 64, _d + 4096);                                            \
    gload_lds16(_s + 128, _d + 8192);                                           \
    gload_lds16(_s + 192, _d + 12288);                                          \
  } while (0)

  STAGE(0);
  STAGE(1);

#define BODY(S, VNSTR)                                                          \
  do {                                                                          \
    if ((S) + 2 < 16) STAGE((S) + 2);                                           \
    asm volatile("s_waitcnt vmcnt(" VNSTR ")");                                 \
    __builtin_amdgcn_sched_barrier(0);                                          \
    __builtin_amdgcn_s_barrier();                                               \
    __builtin_amdgcn_sched_barrier(0);                                          \
    const char* _sb = L0 + ((S) % 3) * 16384 + khalf * 512 + l31 * 16;          \
    f32x16 a0A = {}, a0B = {}, a1A = {}, a1B = {};                              \
    __builtin_amdgcn_s_setprio(1);                                              \
    _Pragma("unroll") for (int ks = 0; ks < 8; ++ks) {                          \
      bf16x8 b0 = *(const bf16x8*)(_sb + ks * 1024);                            \
      bf16x8 b1 = *(const bf16x8*)(_sb + (ks + 8) * 1024);                      \
      a0A = __builtin_amdgcn_mfma_f32_32x32x16_bf16(afrag[0][ks], b0, a0A, 0, 0, 0); \
      a1A = __builtin_amdgcn_mfma_f32_32x32x16_bf16(afrag[1][ks], b0, a1A, 0, 0, 0); \
      a0B = __builtin_amdgcn_mfma_f32_32x32x16_bf16(afrag[0][ks + 8], b1, a0B, 0, 0, 0); \
      a1B = __builtin_amdgcn_mfma_f32_32x32x16_bf16(afrag[1][ks + 8], b1, a1B, 0, 0, 0); \
    }                                                                           \
    __builtin_amdgcn_s_setprio(0);                                              \
    const bool is_pos = (slab[abase + ((S) >> 2)] == myLab);                    \
    f32x16 c0 = a0A + a0B;                                                      \
    f32x16 c1 = a1A + a1B;                                                      \
    float vmax = fmaxf(c0[0], c1[0]);                                           \
    _Pragma("unroll") for (int r = 1; r < 16; ++r)                              \
        vmax = fmaxf(vmax, fmaxf(c0[r], c1[r]));                                \
    const bool anyhot = __any(vmax > thr);                                      \
    if (__builtin_expect(is_pos, 0)) {                                          \
      if (!anyhot) {                                                            \
        _Pragma("unroll") for (int t2 = 0; t2 < 2; ++t2) {                      \
          _Pragma("unroll") for (int r = 0; r < 16; ++r) {                      \
            const int rloc = (r & 3) + 8 * (r >> 2) + 4 * khalf;                \
            const int row = wid * 64 + t2 * 32 + rloc;                          \
            float d = (t2 ? c1[r] : c0[r]) - sdiag[row];                        \
            _Pragma("unroll") for (int st = 1; st < 32; st <<= 1)               \
                d += __shfl_xor(d, st);                                         \
            if (l31 == 0) atomicAdd(&sdacc[row], d);                            \
          }                                                                     \
        }                                                                       \
      } else {                                                                  \
        const bool dt = (abase + ((S) >> 2)) == myAnch;                         \
        _Pragma("unroll") for (int t2 = 0; t2 < 2; ++t2) {                      \
          _Pragma("unroll") for (int r = 0; r < 16; ++r) {                      \
            const int rloc = (r & 3) + 8 * (r >> 2) + 4 * khalf;                \
            const int row = wid * 64 + t2 * 32 + rloc;                          \
            const bool isdiag =                                                 \
                dt && (((wid & 1) * 64 + t2 * 32 + rloc) ==                     \
                       (((S) & 3) * 32 + l31));                                 \
            float v = (t2 ? c1[r] : c0[r]);                                     \
            float d = v - sdiag[row];                                           \
            float sd_e = isdiag ? 0.f : d;                                      \
            float e = (!isdiag && d > -40.f) ? __expf(d) : 0.f;                 \
            _Pragma("unroll") for (int st = 1; st < 32; st <<= 1) {             \
              sd_e += __shfl_xor(sd_e, st);                                     \
              e += __shfl_xor(e, st);                                           \
            }                                                                   \
            if (l31 == 0) {                                                     \
              atomicAdd(&sdacc[row], sd_e);                                     \
              if (e != 0.f) atomicAdd(&epacc[row], e);                          \
            }                                                                   \
          }                                                                     \
        }                                                                       \
      }                                                                         \
    } else if (__builtin_expect(anyhot, 0)) {                                   \
      _Pragma("unroll") for (int t2 = 0; t2 < 2; ++t2) {                        \
        _Pragma("unroll") for (int r = 0; r < 16; ++r) {                        \
          const int rloc = (r & 3) + 8 * (r >> 2) + 4 * khalf;                  \
          const int row = wid * 64 + t2 * 32 + rloc;                            \
          float d = (t2 ? c1[r] : c0[r]) - sdiag[row];                          \
          float e = (d > -40.f) ? __expf(d) : 0.f;                              \
          _Pragma("unroll") for (int st = 1; st < 32; st <<= 1)                 \
              e += __shfl_xor(e, st);                                           \
          if (l31 == 0) atomicAdd(&nsacc[row], e);                              \
        }                                                                       \
      }                                                                         \
    }                                                                           \
    __builtin_amdgcn_s_barrier();                                               \
  } while (0)

  BODY(0, "8");  BODY(1, "8");  BODY(2, "8");  BODY(3, "8");
  BODY(4, "8");  BODY(5, "8");  BODY(6, "8");  BODY(7, "8");
  BODY(8, "8");  BODY(9, "8");  BODY(10, "8"); BODY(11, "8");
  BODY(12, "8"); BODY(13, "8"); BODY(14, "4"); BODY(15, "0");

#undef BODY
#undef STAGE

  __syncthreads();
  if (tid < 256) {
    ns_partial[part * N_ROWS + R0 + tid] = nsacc[tid];
    sd_partial[part * N_ROWS + R0 + tid] = sdacc[tid];
    ep_partial[part * N_ROWS + R0 + tid] = epacc[tid];
  }
}

// -------- Kernel 3: per-row combine. 32 blocks x 256 threads, 1 row/thread.
// mean_log_prob_pos = (SD - npos*log(NS+eps) - EP/(NS+eps)) / npos
__global__ void pcl_combine(const int* __restrict__ labels,
                            const float* __restrict__ ns_partial,
                            const float* __restrict__ sd_partial,
                            const float* __restrict__ ep_partial,
                            float* __restrict__ partials) {
  const int tid = threadIdx.x;
  const int row = blockIdx.x * 256 + tid;
  __shared__ int slab[NANCH];
  __shared__ float sred[256];
  if (tid < NANCH) slab[tid] = labels[tid];
  __syncthreads();

  const int lab = slab[row >> 7];
  int cnt = 0;
#pragma unroll
  for (int b = 0; b < NANCH; ++b) cnt += (slab[b] == lab) ? 1 : 0;

  float NS = 0.f, SD = 0.f, EP = 0.f;
#pragma unroll
  for (int p = 0; p < NPART; ++p) {
    NS += ns_partial[p * N_ROWS + row];
    SD += sd_partial[p * N_ROWS + row];
    EP += ep_partial[p * N_ROWS + row];
  }
  const float npos = (float)(cnt * NVIEW - 1);
  const float nse = NS + 1e-10f;
  const float mlpp = (SD - npos * __logf(nse) - EP / nse) / npos;
  sred[tid] = mlpp;
  __syncthreads();
  for (int st = 128; st > 0; st >>= 1) {
    if (tid < st) sred[tid] += sred[tid + st];
    __syncthreads();
  }
  if (tid == 0) partials[blockIdx.x] = sred[0];
}

__global__ void final_reduce(const float* __restrict__ partials, float* __restrict__ out) {
  __shared__ float s[32];
  int t = threadIdx.x;
  if (t < 32) s[t] = partials[t];
  __syncthreads();
  if (t == 0) {
    float sum = 0.f;
    for (int r = 0; r < 32; ++r) sum += s[r];
    out[0] = -(0.1f / 0.07f) * sum / (float)N_ROWS;
  }
}

extern "C" void kernel_launch(void* const* d_in, const int* in_sizes, int n_in,
                              void* d_out, int out_size, void* d_ws, size_t ws_size,
                              hipStream_t stream) {
  const float* feats = (const float*)d_in[0];
  const int* labels = (const int*)d_in[1];
  float* out = (float*)d_out;

  char* base = (char*)d_ws;
  unsigned short* Xb = (unsigned short*)d_ws;                      // 4 MB
  size_t off = (size_t)N_ROWS * DIM * 2;
  float* diag = (float*)(base + off);       off += N_ROWS * 4;     // 32 KB
  float* ns_partial = (float*)(base + off); off += (size_t)NPART * N_ROWS * 4;
  float* sd_partial = (float*)(base + off); off += (size_t)NPART * N_ROWS * 4;
  float* ep_partial = (float*)(base + off); off += (size_t)NPART * N_ROWS * 4;
  float* partials = (float*)(base + off);

  cast_diag_kernel<<<N_ROWS / 4, 256, 0, stream>>>((const float4v*)feats,
                                                   (ushort4v*)Xb, diag);
  pcl_negsum<<<32 * NPART, 256, 0, stream>>>(Xb, labels, diag, ns_partial,
                                             sd_partial, ep_partial);
  pcl_combine<<<N_ROWS / 256, 256, 0, stream>>>(labels, ns_partial, sd_partial,
                                                ep_partial, partials);
  final_reduce<<<1, 64, 0, stream>>>(partials, out);
}

// Round 11
// 105.781 us; speedup vs baseline: 1.2626x; 1.2626x over previous
//
#include <hip/hip_runtime.h>
#include <hip/hip_bf16.h>

#define N_ROWS 8192
#define DIM 256
#define NANCH 64
#define NVIEW 128
#define NPART 8     // column partitions (8 anchors = 1024 cols each)

typedef __attribute__((ext_vector_type(8))) short bf16x8;
typedef __attribute__((ext_vector_type(16))) float f32x16;
typedef __attribute__((ext_vector_type(4))) float float4v;
typedef __attribute__((ext_vector_type(4))) unsigned short ushort4v;

__device__ __forceinline__ unsigned short f2bf(float x) {
  union { float f; unsigned int u; } c; c.f = x;
  unsigned int u = c.u;
  unsigned int r = (u + 0x7fffu + ((u >> 16) & 1u)) >> 16;
  return (unsigned short)r;
}

__device__ __forceinline__ float bf2f(unsigned short b) {
  union { unsigned int u; float f; } c; c.u = ((unsigned int)b) << 16;
  return c.f;
}

__device__ __forceinline__ void gload_lds16(const void* g, void* l) {
  __builtin_amdgcn_global_load_lds(
      (const __attribute__((address_space(1))) unsigned int*)g,
      (__attribute__((address_space(3))) unsigned int*)l, 16, 0, 0);
}

// fp32 -> bf16 with 1/sqrt(T) prescale, fused with per-row squared-norm
// (= the Gram diagonal = the row max of the logits). One wave per row.
__global__ void cast_diag_kernel(const float4v* __restrict__ in,
                                 ushort4v* __restrict__ out,
                                 float* __restrict__ diag) {
  const int w = threadIdx.x >> 6;
  const int l = threadIdx.x & 63;
  const int row = blockIdx.x * 4 + w;
  const float s = 3.16227766016838f; // 1/sqrt(0.1)
  float4v v = in[row * 64 + l];
  ushort4v o;
  o.x = f2bf(v.x * s);
  o.y = f2bf(v.y * s);
  o.z = f2bf(v.z * s);
  o.w = f2bf(v.w * s);
  out[row * 64 + l] = o;
  float c0 = bf2f(o.x), c1 = bf2f(o.y), c2 = bf2f(o.z), c3 = bf2f(o.w);
  float ss = c0 * c0 + c1 * c1 + c2 * c2 + c3 * c3;
#pragma unroll
  for (int st = 1; st < 64; st <<= 1) ss += __shfl_xor(ss, st);
  if (l == 0) diag[row] = ss;
}

// -------- Kernel 2: fused pass over (256 rows x 1024 cols) per block.
// grid = 32 row-blocks x 8 parts = 256 blocks = exactly 1/CU (co-residency
// of 2 blocks NEVER materialized in rounds 4-10; stop relying on it).
// 512 threads = 8 waves (4 row-groups x 2 col-strips); each wave owns
// 64 rows x its PRIVATE 32-col strip and streams B through a PRIVATE 2-slot
// LDS ring (2 x 8 KB, k-major conflict-free). NO s_barrier in the main loop:
// a wave waits only its own vmcnt (per-wave counter) for its own
// global_load_lds writes -> the 8 waves drift freely and 2 waves/SIMD hide
// each other's latency. 4 independent MFMA chains (depth 8). Row max is
// KNOWN (= diag). Verified fused epilogue (R9/R10):
//   NEG anchors -> ns += exp(v - diag)   [underflow-skipped]
//   POS anchors -> sd += (v - diag); ep += exp(v - diag) [diag masked]
__global__ __launch_bounds__(512, 2) void pcl_negsum(
    const unsigned short* __restrict__ Xb, const int* __restrict__ labels,
    const float* __restrict__ diag, float* __restrict__ ns_partial,
    float* __restrict__ sd_partial, float* __restrict__ ep_partial) {
  const int bx = blockIdx.x;
  const int part = bx & 7;            // same part -> same XCD (L2 panel reuse)
  const int rb = bx >> 3;             // rows rb*256 .. +255
  const int abase = part * 8;         // 8 col-anchors = 1024 cols
  const int tid = threadIdx.x;        // 0..511
  const int wid = tid >> 6;           // 0..7
  const int lane = tid & 63;
  const int l31 = lane & 31;
  const int khalf = lane >> 5;
  const int rg = wid >> 1;            // row group (64 rows)
  const int cg = wid & 1;             // col strip within each 64-col chunk
  const int R0 = rb * 256;

  __shared__ __align__(16) unsigned short ring[8][2][4096];  // 8 x 2 x 8 KB
  __shared__ float sdiag[256];
  __shared__ float nsacc[256];
  __shared__ float sdacc[256];
  __shared__ float epacc[256];
  __shared__ int slab[NANCH];

  if (tid < NANCH) slab[tid] = labels[tid];
  if (tid < 256) {
    sdiag[tid] = diag[R0 + tid];
    nsacc[tid] = 0.f;
    sdacc[tid] = 0.f;
    epacc[tid] = 0.f;
  }
  __syncthreads();
  const int myAnch = rb * 2 + (rg >> 1);  // wave's 64 rows lie in this anchor
  const int myLab = slab[myAnch];

  // A fragments: lane holds row R0 + rg*64 + ri*32 + l31, k = ks*16+khalf*8.
  bf16x8 afrag[2][16];
#pragma unroll
  for (int ri = 0; ri < 2; ++ri) {
#pragma unroll
    for (int ks = 0; ks < 16; ++ks) {
      const unsigned short* p =
          Xb + (size_t)(R0 + rg * 64 + ri * 32 + l31) * DIM + ks * 16 + khalf * 8;
      afrag[ri][ks] = *(const bf16x8*)p;
    }
  }
#pragma unroll
  for (int ri = 0; ri < 2; ++ri)
#pragma unroll
    for (int ks = 0; ks < 16; ++ks) asm volatile("" : "+v"(afrag[ri][ks]));

  // Wave-uniform skip threshold: min diag over this wave's 64 rows - 40.
  float thr;
  {
    float d = sdiag[rg * 64 + lane];
#pragma unroll
    for (int st = 1; st < 64; st <<= 1) d = fminf(d, __shfl_xor(d, st));
    thr = d - 40.f;
  }

  char* const myring = (char*)&ring[wid][0][0];  // 16 KB private

  // Step s (0..31): tile t = s>>1 (32 cols), K-half kh = s&1 (128 k).
  // Private k-major LDS slot [k-octet 0..15][16B x 32 cols]: staged so that
  // chunk g = i*64 + lane -> ko = i*2 + khalf, col = l31 (per-lane source,
  // wave-uniform LDS dest + lane*16 per HW). Conflict-free b128 reads.
#define STAGE(S)                                                                \
  do {                                                                          \
    const int _ts = (S) >> 1, _kh = (S) & 1;                                    \
    const unsigned short* _s =                                                  \
        Xb + (size_t)(part * 1024 + _ts * 64 + cg * 32 + l31) * DIM +           \
        _kh * 128 + khalf * 8;                                                  \
    char* _d = myring + _kh * 8192;                                             \
    _Pragma("unroll") for (int i = 0; i < 8; ++i)                               \
        gload_lds16(_s + i * 16, _d + i * 1024);                                \
  } while (0)

#define MFMA32(A, B, C) __builtin_amdgcn_mfma_f32_32x32x16_bf16(A, B, C, 0, 0, 0)

  STAGE(0);

#pragma unroll
  for (int t = 0; t < 16; ++t) {
    STAGE(2 * t + 1);
    __builtin_amdgcn_sched_barrier(0);
    asm volatile("s_waitcnt vmcnt(8)");   // own loads: drain step 2t
    __builtin_amdgcn_sched_barrier(0);

    f32x16 a0A = {}, a0B = {}, a1A = {}, a1B = {};
    const char* sb0 = myring;             // slot 0 (K-half 0)
    __builtin_amdgcn_s_setprio(1);
#pragma unroll
    for (int ks = 0; ks < 8; ks += 2) {
      bf16x8 b0 = *(const bf16x8*)(sb0 + (ks * 2 + khalf) * 512 + l31 * 16);
      bf16x8 b1 = *(const bf16x8*)(sb0 + ((ks + 1) * 2 + khalf) * 512 + l31 * 16);
      a0A = MFMA32(afrag[0][ks], b0, a0A);
      a1A = MFMA32(afrag[1][ks], b0, a1A);
      a0B = MFMA32(afrag[0][ks + 1], b1, a0B);
      a1B = MFMA32(afrag[1][ks + 1], b1, a1B);
    }
    __builtin_amdgcn_s_setprio(0);

    if (t < 15) {
      STAGE(2 * t + 2);                   // overwrites slot 0 (reads consumed)
      __builtin_amdgcn_sched_barrier(0);
      asm volatile("s_waitcnt vmcnt(8)"); // drain step 2t+1
      __builtin_amdgcn_sched_barrier(0);
    } else {
      __builtin_amdgcn_sched_barrier(0);
      asm volatile("s_waitcnt vmcnt(0)");
      __builtin_amdgcn_sched_barrier(0);
    }

    const char* sb1 = myring + 8192;      // slot 1 (K-half 1)
    __builtin_amdgcn_s_setprio(1);
#pragma unroll
    for (int ks = 0; ks < 8; ks += 2) {
      bf16x8 b0 = *(const bf16x8*)(sb1 + (ks * 2 + khalf) * 512 + l31 * 16);
      bf16x8 b1 = *(const bf16x8*)(sb1 + ((ks + 1) * 2 + khalf) * 512 + l31 * 16);
      a0A = MFMA32(afrag[0][8 + ks], b0, a0A);
      a1A = MFMA32(afrag[1][8 + ks], b0, a1A);
      a0B = MFMA32(afrag[0][8 + ks + 1], b1, a0B);
      a1B = MFMA32(afrag[1][8 + ks + 1], b1, a1B);
    }
    __builtin_amdgcn_s_setprio(0);

    // ---- epilogue for tile t (barrier-free: LDS atomics) ----
    {
      const int aT = abase + (t >> 1);
      const bool is_pos = (slab[aT] == myLab);
      f32x16 c0 = a0A + a0B;
      f32x16 c1 = a1A + a1B;
      float vmax = fmaxf(c0[0], c1[0]);
#pragma unroll
      for (int r = 1; r < 16; ++r) vmax = fmaxf(vmax, fmaxf(c0[r], c1[r]));
      const bool anyhot = __any(vmax > thr);
      const int gcol = part * 1024 + t * 64 + cg * 32 + l31;
      if (__builtin_expect(is_pos, 0)) {
        if (!anyhot) {
#pragma unroll
          for (int ri = 0; ri < 2; ++ri) {
#pragma unroll
            for (int r = 0; r < 16; ++r) {
              const int rloc = (r & 3) + 8 * (r >> 2) + 4 * khalf;
              const int row = rg * 64 + ri * 32 + rloc;
              float d = (ri ? c1[r] : c0[r]) - sdiag[row];
#pragma unroll
              for (int st = 1; st < 32; st <<= 1) d += __shfl_xor(d, st);
              if (l31 == 0) atomicAdd(&sdacc[row], d);
            }
          }
        } else {
#pragma unroll
          for (int ri = 0; ri < 2; ++ri) {
#pragma unroll
            for (int r = 0; r < 16; ++r) {
              const int rloc = (r & 3) + 8 * (r >> 2) + 4 * khalf;
              const int row = rg * 64 + ri * 32 + rloc;
              const bool isdiag = (R0 + row) == gcol;
              float v = (ri ? c1[r] : c0[r]);
              float d = v - sdiag[row];
              float sd_e = isdiag ? 0.f : d;
              float e = (!isdiag && d > -40.f) ? __expf(d) : 0.f;
#pragma unroll
              for (int st = 1; st < 32; st <<= 1) {
                sd_e += __shfl_xor(sd_e, st);
                e += __shfl_xor(e, st);
              }
              if (l31 == 0) {
                atomicAdd(&sdacc[row], sd_e);
                if (e != 0.f) atomicAdd(&epacc[row], e);
              }
            }
          }
        }
      } else if (__builtin_expect(anyhot, 0)) {
#pragma unroll
        for (int ri = 0; ri < 2; ++ri) {
#pragma unroll
          for (int r = 0; r < 16; ++r) {
            const int rloc = (r & 3) + 8 * (r >> 2) + 4 * khalf;
            const int row = rg * 64 + ri * 32 + rloc;
            float d = (ri ? c1[r] : c0[r]) - sdiag[row];
            float e = (d > -40.f) ? __expf(d) : 0.f;
#pragma unroll
            for (int st = 1; st < 32; st <<= 1) e += __shfl_xor(e, st);
            if (l31 == 0) atomicAdd(&nsacc[row], e);
          }
        }
      }
    }
  }

#undef MFMA32
#undef STAGE

  __syncthreads();
  if (tid < 256) {
    ns_partial[part * N_ROWS + R0 + tid] = nsacc[tid];
    sd_partial[part * N_ROWS + R0 + tid] = sdacc[tid];
    ep_partial[part * N_ROWS + R0 + tid] = epacc[tid];
  }
}

// -------- Kernel 3: per-row combine. 32 blocks x 256 threads, 1 row/thread.
// mean_log_prob_pos = (SD - npos*log(NS+eps) - EP/(NS+eps)) / npos
__global__ void pcl_combine(const int* __restrict__ labels,
                            const float* __restrict__ ns_partial,
                            const float* __restrict__ sd_partial,
                            const float* __restrict__ ep_partial,
                            float* __restrict__ partials) {
  const int tid = threadIdx.x;
  const int row = blockIdx.x * 256 + tid;
  __shared__ int slab[NANCH];
  __shared__ float sred[256];
  if (tid < NANCH) slab[tid] = labels[tid];
  __syncthreads();

  const int lab = slab[row >> 7];
  int cnt = 0;
#pragma unroll
  for (int b = 0; b < NANCH; ++b) cnt += (slab[b] == lab) ? 1 : 0;

  float NS = 0.f, SD = 0.f, EP = 0.f;
#pragma unroll
  for (int p = 0; p < NPART; ++p) {
    NS += ns_partial[p * N_ROWS + row];
    SD += sd_partial[p * N_ROWS + row];
    EP += ep_partial[p * N_ROWS + row];
  }
  const float npos = (float)(cnt * NVIEW - 1);
  const float nse = NS + 1e-10f;
  const float mlpp = (SD - npos * __logf(nse) - EP / nse) / npos;
  sred[tid] = mlpp;
  __syncthreads();
  for (int st = 128; st > 0; st >>= 1) {
    if (tid < st) sred[tid] += sred[tid + st];
    __syncthreads();
  }
  if (tid == 0) partials[blockIdx.x] = sred[0];
}

__global__ void final_reduce(const float* __restrict__ partials, float* __restrict__ out) {
  __shared__ float s[32];
  int t = threadIdx.x;
  if (t < 32) s[t] = partials[t];
  __syncthreads();
  if (t == 0) {
    float sum = 0.f;
    for (int r = 0; r < 32; ++r) sum += s[r];
    out[0] = -(0.1f / 0.07f) * sum / (float)N_ROWS;
  }
}

extern "C" void kernel_launch(void* const* d_in, const int* in_sizes, int n_in,
                              void* d_out, int out_size, void* d_ws, size_t ws_size,
                              hipStream_t stream) {
  const float* feats = (const float*)d_in[0];
  const int* labels = (const int*)d_in[1];
  float* out = (float*)d_out;

  char* base = (char*)d_ws;
  unsigned short* Xb = (unsigned short*)d_ws;                      // 4 MB
  size_t off = (size_t)N_ROWS * DIM * 2;
  float* diag = (float*)(base + off);       off += N_ROWS * 4;     // 32 KB
  float* ns_partial = (float*)(base + off); off += (size_t)NPART * N_ROWS * 4;
  float* sd_partial = (float*)(base + off); off += (size_t)NPART * N_ROWS * 4;
  float* ep_partial = (float*)(base + off); off += (size_t)NPART * N_ROWS * 4;
  float* partials = (float*)(base + off);

  cast_diag_kernel<<<N_ROWS / 4, 256, 0, stream>>>((const float4v*)feats,
                                                   (ushort4v*)Xb, diag);
  pcl_negsum<<<32 * NPART, 512, 0, stream>>>(Xb, labels, diag, ns_partial,
                                             sd_partial, ep_partial);
  pcl_combine<<<N_ROWS / 256, 256, 0, stream>>>(labels, ns_partial, sd_partial,
                                                ep_partial, partials);
  final_reduce<<<1, 64, 0, stream>>>(partials, out);
}